// Round 2
// baseline (634.579 us; speedup 1.0000x reference)
//
#include <hip/hip_runtime.h>

// GRU4REC v6: all-LDS recurrence. B=1024, T=256, D=64, H=128.
// 256 blocks x 512 threads (8 waves), 1 block/CU, 4 rows/block (M-pad to 16).
//
// v5 -> v6 (theory: vmcnt counter-coupling kept the HBM gather latency on
// the critical path every step; x is recurrence-independent, so hoist it):
//  * Prologue gathers the block's ENTIRE x sequence (4 rows x maxlen x 64)
//    into LDS as fp16: XT[256][4][64] = 128 KiB. Independent float4 loads,
//    4-way batched for MLP -> HBM-BW bound burst (~10-15 us chip-wide).
//  * Main loop has ZERO global-memory instructions -> no vmcnt waits at
//    all. Per-step x-commit is a conflict-free LDS->LDS u16 copy (phase 2,
//    off the critical path).
//  * Dependent MFMA chains split: gate 6-deep -> 2x3-deep (aR0/aR1,
//    aU0/aU1), cand 4-deep -> 2x2-deep, summed at the end.
// LDS: XT 131072 + XA 6656 + XC 6656 + SIDX 4096 = 148480 B (<160 KiB/CU).
// Weights persist as B-fragments (18 half8 = 72 VGPR).

#define T_   256
#define D_   64
#define H_   128
#define SROW 208   // halves per A-row (416 B), 16B-aligned

typedef _Float16 half8_t  __attribute__((ext_vector_type(8)));
typedef _Float16 half4_t  __attribute__((ext_vector_type(4)));
typedef float    floatx4  __attribute__((ext_vector_type(4)));

__global__ __launch_bounds__(512, 2) void gru_mfma(
    const int* __restrict__ item_his,          // [1024][256]
    const int* __restrict__ seq_lens,          // [1024]
    const float* __restrict__ emb,             // [1e6][64]
    const float* __restrict__ Wg,              // [192][256]
    const float* __restrict__ bg,              // [256]
    const float* __restrict__ Wc,              // [192][128]
    const float* __restrict__ bc,              // [128]
    float* __restrict__ out)                   // [1024][128] fp32
{
    __shared__ __align__(16) _Float16 XT[T_][4][D_];   // x_t, fp16: 128 KiB
    __shared__ __align__(16) _Float16 XA[16][SROW];    // [x | h]   (gate + cand-x A)
    __shared__ __align__(16) _Float16 XC[16][SROW];    // [0 | r*h] (cand-rh A)
    __shared__ int SIDX[4][T_];                        // staged item indices

    const int tid  = threadIdx.x;
    const int w    = tid >> 6;        // wave 0..7
    const int lane = tid & 63;
    const int row0 = blockIdx.x * 4;

    // ---- persistent B-fragments ----
    // B-frag (K32xN16): lane holds B[k = kt*32 + (lane>>4)*8 + i][n = lane&15]
    const int bq = lane >> 4;
    const int bn = lane & 15;
    half8_t BG0[6], BG1[6], BC6[6];   // gate-r (nt=w), gate-u (nt=w+8), cand (nt=w)
    #pragma unroll
    for (int kt = 0; kt < 6; ++kt) {
        half8_t f0, f1, fc;
        #pragma unroll
        for (int i = 0; i < 8; ++i) {
            const int k = kt * 32 + bq * 8 + i;
            f0[i] = (_Float16)Wg[k * 256 + (w * 16 + bn)];
            f1[i] = (_Float16)Wg[k * 256 + (128 + w * 16 + bn)];
            fc[i] = (_Float16)Wc[k * 128 + (w * 16 + bn)];
        }
        BG0[kt] = f0; BG1[kt] = f1; BC6[kt] = fc;
    }

    // ---- biases for this wave's columns (col = lane&15) ----
    const float bgR = bg[w * 16 + bn];
    const float bgU = bg[128 + w * 16 + bn];
    const float bcC = bc[w * 16 + bn];

    // ---- sequence lengths ----
    int len[4];
    #pragma unroll
    for (int r = 0; r < 4; ++r) len[r] = seq_lens[row0 + r];
    const int maxlen = max(max(len[0], len[1]), max(len[2], len[3]));

    // ---- stage indices + zero A-buffers ----
    for (int j = tid; j < 4 * T_; j += 512)
        SIDX[j >> 8][j & 255] = item_his[(row0 + (j >> 8)) * T_ + (j & 255)];
    {
        unsigned* pa = (unsigned*)&XA[0][0];
        unsigned* pc = (unsigned*)&XC[0][0];
        for (int i = tid; i < 16 * SROW / 2; i += 512) { pa[i] = 0u; pc[i] = 0u; }
    }
    __syncthreads();

    // ---- prologue gather: XT[t][r][d] <- (f16)emb[item_his[r][t]][d] ----
    // float4 granularity: flat i -> t = i>>6, r = (i>>4)&3, dq = i&15.
    // 4-way batched so 4 independent HBM loads are in flight per thread.
    {
        const int nq = maxlen << 6;                    // float4 count
        for (int i0 = tid; i0 < nq; i0 += 2048) {
            int id[4];
            #pragma unroll
            for (int uu = 0; uu < 4; ++uu) {
                const int i = i0 + (uu << 9);
                if (i < nq) id[uu] = SIDX[(i >> 4) & 3][i >> 6];
            }
            float4 v[4];
            #pragma unroll
            for (int uu = 0; uu < 4; ++uu) {
                const int i = i0 + (uu << 9);
                if (i < nq)
                    v[uu] = *(const float4*)&emb[(size_t)id[uu] * D_ + ((i & 15) << 2)];
            }
            #pragma unroll
            for (int uu = 0; uu < 4; ++uu) {
                const int i = i0 + (uu << 9);
                if (i < nq) {
                    half4_t hv;
                    hv[0] = (_Float16)v[uu].x; hv[1] = (_Float16)v[uu].y;
                    hv[2] = (_Float16)v[uu].z; hv[3] = (_Float16)v[uu].w;
                    *(half4_t*)&XT[i >> 6][(i >> 4) & 3][(i & 15) << 2] = hv;
                }
            }
        }
    }
    __syncthreads();

    // ---- x-copy mapping: 8 waves x lanes 0..31 cover 4 rows x 64 dims ----
    const int  row_l = w >> 1;
    const int  d_l   = (w & 1) * 32 + (lane & 31);
    const bool ldr   = (lane < 32);

    if (ldr && maxlen > 0) XA[row_l][d_l] = XT[0][row_l][d_l];
    float h[4] = {0.f, 0.f, 0.f, 0.f};
    __syncthreads();

    for (int t = 0; t < maxlen; ++t) {
        // ================= Phase 1: gate + cand-x =================
        half8_t af[6];
        #pragma unroll
        for (int kt = 0; kt < 6; ++kt)
            af[kt] = *(const half8_t*)&XA[lane & 15][kt * 32 + (lane >> 4) * 8];

        floatx4 aR0 = {bgR, bgR, bgR, bgR};
        floatx4 aU0 = {bgU, bgU, bgU, bgU};
        floatx4 aCx = {bcC, bcC, bcC, bcC};
        floatx4 aR1 = {0.f, 0.f, 0.f, 0.f};
        floatx4 aU1 = {0.f, 0.f, 0.f, 0.f};
        // two interleaved 3-deep chains per gate output
        aR0 = __builtin_amdgcn_mfma_f32_16x16x32_f16(af[0], BG0[0], aR0, 0, 0, 0);
        aU0 = __builtin_amdgcn_mfma_f32_16x16x32_f16(af[0], BG1[0], aU0, 0, 0, 0);
        aCx = __builtin_amdgcn_mfma_f32_16x16x32_f16(af[0], BC6[0], aCx, 0, 0, 0);
        aR1 = __builtin_amdgcn_mfma_f32_16x16x32_f16(af[1], BG0[1], aR1, 0, 0, 0);
        aU1 = __builtin_amdgcn_mfma_f32_16x16x32_f16(af[1], BG1[1], aU1, 0, 0, 0);
        aCx = __builtin_amdgcn_mfma_f32_16x16x32_f16(af[1], BC6[1], aCx, 0, 0, 0);
        aR0 = __builtin_amdgcn_mfma_f32_16x16x32_f16(af[2], BG0[2], aR0, 0, 0, 0);
        aU0 = __builtin_amdgcn_mfma_f32_16x16x32_f16(af[2], BG1[2], aU0, 0, 0, 0);
        aR1 = __builtin_amdgcn_mfma_f32_16x16x32_f16(af[3], BG0[3], aR1, 0, 0, 0);
        aU1 = __builtin_amdgcn_mfma_f32_16x16x32_f16(af[3], BG1[3], aU1, 0, 0, 0);
        aR0 = __builtin_amdgcn_mfma_f32_16x16x32_f16(af[4], BG0[4], aR0, 0, 0, 0);
        aU0 = __builtin_amdgcn_mfma_f32_16x16x32_f16(af[4], BG1[4], aU0, 0, 0, 0);
        aR1 = __builtin_amdgcn_mfma_f32_16x16x32_f16(af[5], BG0[5], aR1, 0, 0, 0);
        aU1 = __builtin_amdgcn_mfma_f32_16x16x32_f16(af[5], BG1[5], aU1, 0, 0, 0);
        const floatx4 aR = aR0 + aR1;
        const floatx4 aU = aU0 + aU1;

        float u[4];
        if (lane < 16) {
            #pragma unroll
            for (int r = 0; r < 4; ++r) {
                const float rg = 1.f / (1.f + __expf(-aR[r]));
                u[r]           = 1.f / (1.f + __expf(-aU[r]));
                XC[r][64 + w * 16 + lane] = (_Float16)(rg * h[r]);   // r * h
            }
        }
        __syncthreads();

        // ================= Phase 2: cand-rh + h update =================
        // commit x_{t+1} for next step's gate (LDS->LDS, off critical path;
        // at t = maxlen-1 this copies unused data — harmless, in-bounds).
        if (ldr) XA[row_l][d_l] = XT[t + 1][row_l][d_l];

        half8_t cf[4];
        #pragma unroll
        for (int kk = 0; kk < 4; ++kk)
            cf[kk] = *(const half8_t*)&XC[lane & 15][(kk + 2) * 32 + (lane >> 4) * 8];
        floatx4 aC0 = aCx;
        floatx4 aC1 = {0.f, 0.f, 0.f, 0.f};
        aC0 = __builtin_amdgcn_mfma_f32_16x16x32_f16(cf[0], BC6[2], aC0, 0, 0, 0);
        aC1 = __builtin_amdgcn_mfma_f32_16x16x32_f16(cf[1], BC6[3], aC1, 0, 0, 0);
        aC0 = __builtin_amdgcn_mfma_f32_16x16x32_f16(cf[2], BC6[4], aC0, 0, 0, 0);
        aC1 = __builtin_amdgcn_mfma_f32_16x16x32_f16(cf[3], BC6[5], aC1, 0, 0, 0);
        const floatx4 aC = aC0 + aC1;

        if (lane < 16) {
            #pragma unroll
            for (int r = 0; r < 4; ++r) {
                float s = aC[r];
                s = fminf(fmaxf(s, -15.f), 15.f);
                const float e = __expf(2.f * s);
                const float c = (e - 1.f) / (e + 1.f);          // tanh
                const float hn = u[r] * h[r] + (1.f - u[r]) * c;
                if (t < len[r]) h[r] = hn;                       // copy-through mask
                XA[r][64 + w * 16 + lane] = (_Float16)h[r];
            }
        }
        __syncthreads();
    }

    // ---- write final h (fp32): wave w covers cols [16w, 16w+16) ----
    if (lane < 16) {
        #pragma unroll
        for (int r = 0; r < 4; ++r)
            out[(row0 + r) * H_ + w * 16 + lane] = h[r];
    }
}

extern "C" void kernel_launch(void* const* d_in, const int* in_sizes, int n_in,
                              void* d_out, int out_size, void* d_ws, size_t ws_size,
                              hipStream_t stream) {
    const int*   item_his = (const int*)d_in[0];
    const int*   seq_lens = (const int*)d_in[1];
    const float* emb      = (const float*)d_in[2];
    const float* Wg       = (const float*)d_in[3];
    const float* bg       = (const float*)d_in[4];
    const float* Wc       = (const float*)d_in[5];
    const float* bc       = (const float*)d_in[6];
    float*       out      = (float*)d_out;

    gru_mfma<<<256, 512, 0, stream>>>(item_his, seq_lens, emb, Wg, bg, Wc, bc, out);
}

// Round 3
// 595.212 us; speedup vs baseline: 1.0661x; 1.0661x over previous
//
#include <hip/hip_runtime.h>

// GRU4REC v7: latency-lean recurrence. B=1024, T=256, D=64, H=128.
// 256 blocks x 256 threads (4 waves), 1 block/CU, 4 rows/block (M-pad 16).
//
// v6 -> v7 (theory: step time is LDS-pipe contention from 8x-redundant
// A-fragment reads + full-precision division chains in the activations;
// the HBM gather was never on the critical path — v6 proved that):
//  * 4 waves, each owning 2 N-tiles of r/u/c (cols 32w..32w+32): redundant
//    A-reads halve (24+16 b128/step vs 48+32), barrier has 4 participants,
//    1 wave/SIMD -> 512-VGPR budget for 36 half8 weight fragments.
//  * All divisions -> __builtin_amdgcn_rcpf (~1 ulp; negligible vs fp16):
//    sigmoid = rcp(1+exp(-x)), tanh = 1 - 2*rcp(1+exp(2s)). Kills the
//    v_div_scale/fmas/fixup chains on the critical path.
//  * u-gate sigmoid deferred to phase 2 (overlaps cand MFMA latency).
//  * h-blend as one FMA: h' = c + u*(h-c).
//  * x-commit: ONE wave does 64 x b64 LDS->LDS (2 ops) instead of 256 b16.
// LDS: XT 131072 + XA 6656 + XC 6656 = 144384 B.
// MFMA per step unchanged (144 total): gate 96 + cand-x 16 + cand-rh 32.

#define T_   256
#define D_   64
#define H_   128
#define SROW 208   // halves per A-row (416 B) — v4-proven conflict-free

typedef _Float16 half8_t  __attribute__((ext_vector_type(8)));
typedef _Float16 half4_t  __attribute__((ext_vector_type(4)));
typedef float    floatx4  __attribute__((ext_vector_type(4)));

__device__ __forceinline__ float fast_sigmoid(float x) {
    // 1/(1+e^-x); hw rcp is ~1ulp — irrelevant vs fp16 input rounding
    return __builtin_amdgcn_rcpf(1.f + __expf(-x));
}
__device__ __forceinline__ float fast_tanh(float s) {
    s = fminf(fmaxf(s, -15.f), 15.f);
    return 1.f - 2.f * __builtin_amdgcn_rcpf(1.f + __expf(2.f * s));
}

__global__ __launch_bounds__(256, 1) void gru_mfma(
    const int* __restrict__ item_his,          // [1024][256]
    const int* __restrict__ seq_lens,          // [1024]
    const float* __restrict__ emb,             // [1e6][64]
    const float* __restrict__ Wg,              // [192][256]
    const float* __restrict__ bg,              // [256]
    const float* __restrict__ Wc,              // [192][128]
    const float* __restrict__ bc,              // [128]
    float* __restrict__ out)                   // [1024][128] fp32
{
    __shared__ __align__(16) _Float16 XT[T_][4][D_];   // x_t fp16, 128 KiB
    __shared__ __align__(16) _Float16 XA[16][SROW];    // [x | h]      (gate A)
    __shared__ __align__(16) _Float16 XC[16][SROW];    // [r*h | pad]  (cand-rh A)

    const int tid  = threadIdx.x;
    const int w    = tid >> 6;        // wave 0..3
    const int lane = tid & 63;
    const int row0 = blockIdx.x * 4;

    const int bq = lane >> 4;         // k-quad
    const int bn = lane & 15;         // n within tile / A-row

    // ---- persistent B-fragments: wave w owns tiles (2w, 2w+1) ----
    // B-frag (K32xN16): lane holds B[k = kt*32 + bq*8 + i][n = tile*16 + bn]
    half8_t BG0[2][6], BG1[2][6], BC6[2][6];
    #pragma unroll
    for (int j = 0; j < 2; ++j) {
        const int col = (2 * w + j) * 16 + bn;
        #pragma unroll
        for (int kt = 0; kt < 6; ++kt) {
            half8_t f0, f1, fc;
            #pragma unroll
            for (int i = 0; i < 8; ++i) {
                const int k = kt * 32 + bq * 8 + i;
                f0[i] = (_Float16)Wg[k * 256 + col];
                f1[i] = (_Float16)Wg[k * 256 + 128 + col];
                fc[i] = (_Float16)Wc[k * 128 + col];
            }
            BG0[j][kt] = f0; BG1[j][kt] = f1; BC6[j][kt] = fc;
        }
    }

    float bgR[2], bgU[2], bcC[2];
    #pragma unroll
    for (int j = 0; j < 2; ++j) {
        const int col = (2 * w + j) * 16 + bn;
        bgR[j] = bg[col];
        bgU[j] = bg[128 + col];
        bcC[j] = bc[col];
    }

    // ---- sequence lengths ----
    int len[4];
    #pragma unroll
    for (int r = 0; r < 4; ++r) len[r] = seq_lens[row0 + r];
    const int maxlen = max(max(len[0], len[1]), max(len[2], len[3]));

    // ---- zero A-buffers (rows 4..15 stay zero forever) ----
    {
        unsigned* pa = (unsigned*)&XA[0][0];
        unsigned* pc = (unsigned*)&XC[0][0];
        for (int i = tid; i < 16 * SROW / 2; i += 256) { pa[i] = 0u; pc[i] = 0u; }
    }

    // ---- prologue gather: XT[t][r][d] <- (f16)emb[item_his[r][t]][d] ----
    // float4 units: t = i>>6, r = (i>>4)&3, dq = i&15. 8-deep batched.
    {
        const int nq = maxlen << 6;
        for (int i0 = tid; i0 < nq; i0 += 2048) {
            int id[8];
            #pragma unroll
            for (int b = 0; b < 8; ++b) {
                const int i = i0 + (b << 8);
                if (i < nq) id[b] = item_his[(row0 + ((i >> 4) & 3)) * T_ + (i >> 6)];
            }
            float4 v[8];
            #pragma unroll
            for (int b = 0; b < 8; ++b) {
                const int i = i0 + (b << 8);
                if (i < nq)
                    v[b] = *(const float4*)&emb[(size_t)id[b] * D_ + ((i & 15) << 2)];
            }
            #pragma unroll
            for (int b = 0; b < 8; ++b) {
                const int i = i0 + (b << 8);
                if (i < nq) {
                    half4_t hv;
                    hv[0] = (_Float16)v[b].x; hv[1] = (_Float16)v[b].y;
                    hv[2] = (_Float16)v[b].z; hv[3] = (_Float16)v[b].w;
                    *(half4_t*)&XT[i >> 6][(i >> 4) & 3][(i & 15) << 2] = hv;
                }
            }
        }
    }
    __syncthreads();

    // ---- x_0 -> XA x-region: one wave, b64 per lane (4 rows x 64 halves) ----
    if (tid < 64) {
        const half4_t v = *(const half4_t*)&XT[0][tid >> 4][(tid & 15) * 4];
        *(half4_t*)&XA[tid >> 4][(tid & 15) * 4] = v;
    }
    float h[2][4] = {{0.f,0.f,0.f,0.f},{0.f,0.f,0.f,0.f}};
    __syncthreads();

    for (int t = 0; t < maxlen; ++t) {
        // ================= Phase 1: gate + cand-x =================
        half8_t af[6];
        #pragma unroll
        for (int kt = 0; kt < 6; ++kt)
            af[kt] = *(const half8_t*)&XA[bn][kt * 32 + bq * 8];

        floatx4 aR[2], aU[2], aCx[2];
        #pragma unroll
        for (int j = 0; j < 2; ++j) {
            aR[j]  = (floatx4){bgR[j], bgR[j], bgR[j], bgR[j]};
            aU[j]  = (floatx4){bgU[j], bgU[j], bgU[j], bgU[j]};
            aCx[j] = (floatx4){bcC[j], bcC[j], bcC[j], bcC[j]};
        }
        #pragma unroll
        for (int kt = 0; kt < 6; ++kt) {
            #pragma unroll
            for (int j = 0; j < 2; ++j) {
                aR[j] = __builtin_amdgcn_mfma_f32_16x16x32_f16(af[kt], BG0[j][kt], aR[j], 0, 0, 0);
                aU[j] = __builtin_amdgcn_mfma_f32_16x16x32_f16(af[kt], BG1[j][kt], aU[j], 0, 0, 0);
                if (kt < 2)
                    aCx[j] = __builtin_amdgcn_mfma_f32_16x16x32_f16(af[kt], BC6[j][kt], aCx[j], 0, 0, 0);
            }
        }
        // r-gate only on the critical path; u-sigmoid deferred to phase 2.
        if (lane < 16) {
            #pragma unroll
            for (int j = 0; j < 2; ++j)
                #pragma unroll
                for (int r = 0; r < 4; ++r) {
                    const float rg = fast_sigmoid(aR[j][r]);
                    XC[r][(2 * w + j) * 16 + lane] = (_Float16)(rg * h[j][r]);
                }
        }
        __syncthreads();

        // ================= Phase 2: cand-rh + h update =================
        // x_{t+1} -> XA x-region (one wave, 2 LDS ops, off critical path)
        if (tid < 64) {
            const half4_t v = *(const half4_t*)&XT[t + 1][tid >> 4][(tid & 15) * 4];
            *(half4_t*)&XA[tid >> 4][(tid & 15) * 4] = v;
        }
        half8_t cf[4];
        #pragma unroll
        for (int kk = 0; kk < 4; ++kk)
            cf[kk] = *(const half8_t*)&XC[bn][kk * 32 + bq * 8];
        floatx4 aC[2] = {aCx[0], aCx[1]};
        #pragma unroll
        for (int kk = 0; kk < 4; ++kk)
            #pragma unroll
            for (int j = 0; j < 2; ++j)
                aC[j] = __builtin_amdgcn_mfma_f32_16x16x32_f16(cf[kk], BC6[j][kk + 2], aC[j], 0, 0, 0);

        if (lane < 16) {
            #pragma unroll
            for (int j = 0; j < 2; ++j)
                #pragma unroll
                for (int r = 0; r < 4; ++r) {
                    const float ug = fast_sigmoid(aU[j][r]);
                    const float c  = fast_tanh(aC[j][r]);
                    const float hn = c + ug * (h[j][r] - c);
                    if (t < len[r]) h[j][r] = hn;            // copy-through mask
                    XA[r][64 + (2 * w + j) * 16 + lane] = (_Float16)h[j][r];
                }
        }
        __syncthreads();
    }

    // ---- write final h (fp32): wave w covers cols [32w, 32w+32) ----
    if (lane < 16) {
        #pragma unroll
        for (int j = 0; j < 2; ++j)
            #pragma unroll
            for (int r = 0; r < 4; ++r)
                out[(row0 + r) * H_ + (2 * w + j) * 16 + lane] = h[j][r];
    }
}

extern "C" void kernel_launch(void* const* d_in, const int* in_sizes, int n_in,
                              void* d_out, int out_size, void* d_ws, size_t ws_size,
                              hipStream_t stream) {
    const int*   item_his = (const int*)d_in[0];
    const int*   seq_lens = (const int*)d_in[1];
    const float* emb      = (const float*)d_in[2];
    const float* Wg       = (const float*)d_in[3];
    const float* bg       = (const float*)d_in[4];
    const float* Wc       = (const float*)d_in[5];
    const float* bc       = (const float*)d_in[6];
    float*       out      = (float*)d_out;

    gru_mfma<<<256, 256, 0, stream>>>(item_his, seq_lens, emb, Wg, bg, Wc, bc, out);
}